// Round 2
// baseline (361.158 us; speedup 1.0000x reference)
//
#include <hip/hip_runtime.h>
#include <math.h>

#define B 4096
#define C 5
#define NNEG 20
#define D 128
#define NROWS (C + C * NNEG)  // 105 rows per batch element (5 pos + 100 neg)
#define NSLOT 14              // 14 slots x 8 half-waves = 112 row-slots >= 105

// stable log sigmoid: logsig(x) = min(x,0) - log1p(exp(-|x|))
__device__ __forceinline__ float log_sigmoid(float x) {
    return fminf(x, 0.0f) - log1pf(__expf(-fabsf(x)));
}

// One block per batch element. 256 threads = 8 half-waves of 32 lanes.
// KEY CHANGE vs prior round: a row's full 512 B is fetched CONTIGUOUSLY by
// one half-wave in a single instruction (lane l32 takes bytes [16*l32,16*l32+16)),
// so each vmem instruction touches 2 rows x 512B instead of 8 rows x 128B.
// Goal: guarantee all 4 cache lines of a row reach the memory controller
// adjacently -> one DRAM row activate per embedding row (random-gather
// efficiency), instead of interleaved 128B fragments from 8 rows.
// Half-wave hw owns row slots {s*8 + hw, s=0..13}; slots >= 105 are clamped
// to row-slot 0 (L1-hit dummy) and masked out of the accumulation.
__global__ __launch_bounds__(256) void sgns_partial(
    const int* __restrict__ iword,
    const int* __restrict__ owords,
    const int* __restrict__ nwords,
    const float* __restrict__ emb1,
    const float* __restrict__ emb2,
    float* __restrict__ partial)
{
    const int b    = blockIdx.x;
    const int tid  = threadIdx.x;
    const int lane = tid & 63;
    const int wave = tid >> 6;   // 0..3
    const int hw   = tid >> 5;   // half-wave id 0..7
    const int l32  = tid & 31;   // lane within half-wave -> dim slice [4*l32, 4*l32+4)

    // v1 fragment: one contiguous float4 per lane (512B row in one instruction)
    const float4* v1p = (const float4*)(emb1 + (long)iword[b] * D);
    const float4 v1f = v1p[l32];

    // resolve this half-wave's 14 row indices (clamp invalid tail slots)
    int   rIdx[NSLOT];
    float sgn[NSLOT];
    bool  valid[NSLOT];
    #pragma unroll
    for (int s = 0; s < NSLOT; ++s) {
        const int r = s * 8 + hw;
        valid[s] = (r < NROWS);
        const int rr = valid[s] ? r : 0;
        const bool pos = (rr < C);
        sgn[s] = pos ? 1.0f : -1.0f;
        rIdx[s] = pos ? owords[b * C + rr]
                      : nwords[b * (C * NNEG) + (rr - C)];
    }

    // issue all 14 row gathers (full 512B contiguous per row) before consuming
    float4 rw[NSLOT];
    #pragma unroll
    for (int s = 0; s < NSLOT; ++s) {
        rw[s] = ((const float4*)(emb2 + (long)rIdx[s] * D))[l32];
    }

    float acc = 0.0f;
    #pragma unroll
    for (int s = 0; s < NSLOT; ++s) {
        float t = v1f.x * rw[s].x + v1f.y * rw[s].y
                + v1f.z * rw[s].z + v1f.w * rw[s].w;
        // 5-step butterfly across the 32-lane half-wave
        t += __shfl_xor(t, 1, 64);
        t += __shfl_xor(t, 2, 64);
        t += __shfl_xor(t, 4, 64);
        t += __shfl_xor(t, 8, 64);
        t += __shfl_xor(t, 16, 64);
        const float v = log_sigmoid(sgn[s] * t);
        acc += valid[s] ? v : 0.0f;
    }

    // acc is uniform within each half-wave; fold other half, then other waves
    acc += __shfl_xor(acc, 32, 64);   // wave total on every lane

    __shared__ float wsum[4];
    if (lane == 0) wsum[wave] = acc;
    __syncthreads();
    if (tid == 0)
        partial[b] = wsum[0] + wsum[1] + wsum[2] + wsum[3];
}

// Single-block final reduction: out = -(sum of all logsig terms) / (B*C)
__global__ __launch_bounds__(256) void sgns_reduce(
    const float* __restrict__ partial,
    float* __restrict__ out)
{
    const int tid = threadIdx.x;
    float acc = 0.0f;
    for (int i = tid; i < B; i += 256) acc += partial[i];

    #pragma unroll
    for (int off = 32; off > 0; off >>= 1)
        acc += __shfl_xor(acc, off, 64);

    __shared__ float ws[4];
    if ((tid & 63) == 0) ws[tid >> 6] = acc;
    __syncthreads();
    if (tid == 0) out[0] = -(ws[0] + ws[1] + ws[2] + ws[3]) / (float)(B * C);
}

extern "C" void kernel_launch(void* const* d_in, const int* in_sizes, int n_in,
                              void* d_out, int out_size, void* d_ws, size_t ws_size,
                              hipStream_t stream) {
    const int*   iword  = (const int*)d_in[0];
    const int*   owords = (const int*)d_in[1];
    const int*   nwords = (const int*)d_in[2];
    const float* emb1   = (const float*)d_in[3];
    const float* emb2   = (const float*)d_in[4];
    float* out     = (float*)d_out;
    float* partial = (float*)d_ws;  // B floats = 16 KB

    sgns_partial<<<B, 256, 0, stream>>>(iword, owords, nwords, emb1, emb2, partial);
    sgns_reduce<<<1, 256, 0, stream>>>(partial, out);
}